// Round 1
// baseline (968.833 us; speedup 1.0000x reference)
//
#include <hip/hip_runtime.h>

#define N_NODES 100000
#define N_EDGES 3200000
#define DD 256

// ---------------- GEMM: h = x @ W^T  (fp32, 64x64 tile, BK=16) ----------------
#define BM 64
#define BN 64
#define BK 16
#define LDT 68   // padded leading dim for transposed LDS tiles [BK][64+4]

__global__ __launch_bounds__(256) void gemm_kernel(
    const float* __restrict__ x, const float* __restrict__ w, float* __restrict__ h)
{
    __shared__ float xs[BK][LDT];
    __shared__ float wsm[BK][LDT];
    const int tid = threadIdx.x;
    const int bm = blockIdx.x * BM;
    const int bn = blockIdx.y * BN;
    const int r = tid >> 2;          // 0..63
    const int c = (tid & 3) * 4;     // 0,4,8,12
    const int ty = tid >> 4;         // 0..15
    const int tx = tid & 15;         // 0..15
    const int tr = ty * 4;
    const int tc = tx * 4;
    float acc[4][4] = {};
    const int xr = bm + r;
    const bool xok = (xr < N_NODES);
    const float* xrow = x + (size_t)(xok ? xr : 0) * DD;
    const float* wrow = w + (size_t)(bn + r) * DD;

    for (int k0 = 0; k0 < DD; k0 += BK) {
        float4 xv = make_float4(0.f, 0.f, 0.f, 0.f);
        if (xok) xv = *(const float4*)(xrow + k0 + c);
        float4 wv = *(const float4*)(wrow + k0 + c);
        xs[c + 0][r] = xv.x; xs[c + 1][r] = xv.y; xs[c + 2][r] = xv.z; xs[c + 3][r] = xv.w;
        wsm[c + 0][r] = wv.x; wsm[c + 1][r] = wv.y; wsm[c + 2][r] = wv.z; wsm[c + 3][r] = wv.w;
        __syncthreads();
        #pragma unroll
        for (int kk = 0; kk < BK; ++kk) {
            float4 a = *(const float4*)&xs[kk][tr];
            float4 b = *(const float4*)&wsm[kk][tc];
            float av[4] = {a.x, a.y, a.z, a.w};
            float bv[4] = {b.x, b.y, b.z, b.w};
            #pragma unroll
            for (int i = 0; i < 4; ++i)
                #pragma unroll
                for (int j = 0; j < 4; ++j)
                    acc[i][j] += av[i] * bv[j];
        }
        __syncthreads();
    }
    #pragma unroll
    for (int i = 0; i < 4; ++i) {
        int gr = bm + tr + i;
        if (gr < N_NODES)
            *(float4*)(h + (size_t)gr * DD + bn + tc) =
                make_float4(acc[i][0], acc[i][1], acc[i][2], acc[i][3]);
    }
}

// ---------------- edge histogram ----------------
__global__ void hist_kernel(const int* __restrict__ row, int* __restrict__ counts)
{
    int i = blockIdx.x * blockDim.x + threadIdx.x;
    if (i < N_EDGES) atomicAdd(&counts[row[i]], 1);
}

// ---------------- 2-level exclusive scan over counts[N_NODES] ----------------
#define SCAN_B 512

__global__ void scan1_kernel(const int* __restrict__ counts, int* __restrict__ bsum)
{
    __shared__ int lds[SCAN_B];
    int i = blockIdx.x * SCAN_B + threadIdx.x;
    int v = (i < N_NODES) ? counts[i] : 0;
    lds[threadIdx.x] = v;
    __syncthreads();
    for (int s = SCAN_B / 2; s > 0; s >>= 1) {
        if (threadIdx.x < s) lds[threadIdx.x] += lds[threadIdx.x + s];
        __syncthreads();
    }
    if (threadIdx.x == 0) bsum[blockIdx.x] = lds[0];
}

__global__ void scan2_kernel(int* __restrict__ bsum, int nb)
{
    __shared__ int lds[SCAN_B];
    int tid = threadIdx.x;
    int v = (tid < nb) ? bsum[tid] : 0;
    lds[tid] = v;
    __syncthreads();
    for (int s = 1; s < SCAN_B; s <<= 1) {
        int t = (tid >= s) ? lds[tid - s] : 0;
        __syncthreads();
        lds[tid] += t;
        __syncthreads();
    }
    if (tid < nb) bsum[tid] = lds[tid] - v;  // exclusive
}

__global__ void scan3_kernel(const int* __restrict__ counts, const int* __restrict__ bsum,
                             int* __restrict__ row_start, int* __restrict__ cursor)
{
    __shared__ int lds[SCAN_B];
    int tid = threadIdx.x;
    int i = blockIdx.x * SCAN_B + tid;
    int v = (i < N_NODES) ? counts[i] : 0;
    lds[tid] = v;
    __syncthreads();
    for (int s = 1; s < SCAN_B; s <<= 1) {
        int t = (tid >= s) ? lds[tid - s] : 0;
        __syncthreads();
        lds[tid] += t;
        __syncthreads();
    }
    int excl = lds[tid] - v + bsum[blockIdx.x];
    if (i < N_NODES) { row_start[i] = excl; cursor[i] = excl; }
    if (i == N_NODES - 1) row_start[N_NODES] = excl + v;
}

// ---------------- scatter edges into CSR order ----------------
__global__ void scatter_kernel(const int* __restrict__ row, const int* __restrict__ col,
                               const float* __restrict__ val, int* __restrict__ cursor,
                               int* __restrict__ scol, float* __restrict__ sval)
{
    int i = blockIdx.x * blockDim.x + threadIdx.x;
    if (i < N_EDGES) {
        int p = atomicAdd(&cursor[row[i]], 1);
        scol[p] = col[i];
        sval[p] = val[i];
    }
}

// ---------------- SpMM: one wave per output row ----------------
__global__ __launch_bounds__(256) void spmm_kernel(
    const float* __restrict__ h, const int* __restrict__ scol,
    const float* __restrict__ sval, const int* __restrict__ row_start,
    float* __restrict__ out)
{
    const int wid = (blockIdx.x * blockDim.x + threadIdx.x) >> 6;
    const int lane = threadIdx.x & 63;
    if (wid >= N_NODES) return;
    const int s = row_start[wid];
    const int e = row_start[wid + 1];
    float4 acc = make_float4(0.f, 0.f, 0.f, 0.f);
    for (int i = s; i < e; ++i) {
        const int cidx = scol[i];
        const float v = sval[i];
        const float4 hv = *(const float4*)(h + (size_t)cidx * DD + lane * 4);
        acc.x += v * hv.x;
        acc.y += v * hv.y;
        acc.z += v * hv.z;
        acc.w += v * hv.w;
    }
    *(float4*)(out + (size_t)wid * DD + lane * 4) = acc;
}

extern "C" void kernel_launch(void* const* d_in, const int* in_sizes, int n_in,
                              void* d_out, int out_size, void* d_ws, size_t ws_size,
                              hipStream_t stream)
{
    const float* x        = (const float*)d_in[0];
    const float* W        = (const float*)d_in[1];
    const float* edge_val = (const float*)d_in[2];
    const int*   edge_row = (const int*)d_in[3];
    const int*   edge_col = (const int*)d_in[4];
    float* out = (float*)d_out;

    char* ws = (char*)d_ws;
    size_t off = 0;
    auto alloc = [&](size_t bytes) {
        void* p = ws + off;
        off = (off + bytes + 255) & ~(size_t)255;
        return p;
    };
    float* h         = (float*)alloc((size_t)N_NODES * DD * sizeof(float)); // 102.4 MB
    int*   scol      = (int*)  alloc((size_t)N_EDGES * sizeof(int));        // 12.8 MB
    float* sval      = (float*)alloc((size_t)N_EDGES * sizeof(float));      // 12.8 MB
    int*   counts    = (int*)  alloc((size_t)N_NODES * sizeof(int));
    int*   row_start = (int*)  alloc((size_t)(N_NODES + 1) * sizeof(int));
    int*   cursor    = (int*)  alloc((size_t)N_NODES * sizeof(int));
    int*   bsum      = (int*)  alloc(SCAN_B * sizeof(int));
    (void)ws_size;

    hipMemsetAsync(counts, 0, (size_t)N_NODES * sizeof(int), stream);

    // h = x @ W^T
    dim3 ggrid((N_NODES + BM - 1) / BM, DD / BN);
    gemm_kernel<<<ggrid, 256, 0, stream>>>(x, W, h);

    // build CSR
    hist_kernel<<<(N_EDGES + 255) / 256, 256, 0, stream>>>(edge_row, counts);
    int nb = (N_NODES + SCAN_B - 1) / SCAN_B;  // 196
    scan1_kernel<<<nb, SCAN_B, 0, stream>>>(counts, bsum);
    scan2_kernel<<<1, SCAN_B, 0, stream>>>(bsum, nb);
    scan3_kernel<<<nb, SCAN_B, 0, stream>>>(counts, bsum, row_start, cursor);
    scatter_kernel<<<(N_EDGES + 255) / 256, 256, 0, stream>>>(edge_row, edge_col, edge_val,
                                                              cursor, scol, sval);

    // out[r] = sum_e val * h[col]
    int spmm_blocks = (N_NODES * 64 + 255) / 256;  // one wave per row
    spmm_kernel<<<spmm_blocks, 256, 0, stream>>>(h, scol, sval, row_start, out);
}

// Round 2
// 644.996 us; speedup vs baseline: 1.5021x; 1.5021x over previous
//
#include <hip/hip_runtime.h>

typedef float  f32x4 __attribute__((ext_vector_type(4)));
typedef short  s16x8 __attribute__((ext_vector_type(8)));

#define N_NODES 100000
#define N_EDGES 3200000
#define DD 256

__device__ __forceinline__ ushort f2bf(float f) {
    unsigned u = __float_as_uint(f);
    unsigned r = (u + 0x7FFFu + ((u >> 16) & 1u)) >> 16;  // RNE
    return (ushort)r;
}
__device__ __forceinline__ float bf2f(ushort u) {
    return __uint_as_float(((unsigned)u) << 16);
}

// ---------------- W fp32 -> bf16 (256x256) ----------------
__global__ void wconv_kernel(const float* __restrict__ w, ushort* __restrict__ wb)
{
    int i = blockIdx.x * blockDim.x + threadIdx.x;   // 16384 threads, float4 each
    float4 v = ((const float4*)w)[i];
    ushort4 o = make_ushort4(f2bf(v.x), f2bf(v.y), f2bf(v.z), f2bf(v.w));
    ((ushort4*)wb)[i] = o;
}

// ---------------- GEMM: h(bf16) = x @ W^T via MFMA bf16 ----------------
// tile 128x64, BK=128 (two K halves), 4 waves (2x2), wave computes 64x32
#define GBM 128
#define GBN 64
#define LDX 136   // 128 + 8 pad; row stride 272 B (16B-aligned, 2-way banks)

__global__ __launch_bounds__(256) void gemm_mfma(
    const float* __restrict__ x, const ushort* __restrict__ wb, ushort* __restrict__ h)
{
    __shared__ ushort xs[GBM][LDX];
    __shared__ ushort wsx[GBN][LDX];
    const int tid  = threadIdx.x;
    const int lane = tid & 63;
    const int wave = tid >> 6;
    const int wr = wave >> 1, wc = wave & 1;
    const int bm = blockIdx.x * GBM;
    const int bn = blockIdx.y * GBN;
    const int l15 = lane & 15;
    const int lhi = lane >> 4;
    f32x4 acc[4][2] = {};

    for (int k0 = 0; k0 < DD; k0 += 128) {
        // stage x tile (128 rows x 128 k), fp32 -> bf16
        #pragma unroll
        for (int i = 0; i < 16; ++i) {
            int f = (i * 256 + tid) * 4;
            int r = f >> 7;
            int c = f & 127;
            float4 v = make_float4(0.f, 0.f, 0.f, 0.f);
            if (bm + r < N_NODES) v = *(const float4*)(x + (size_t)(bm + r) * DD + k0 + c);
            *(ushort4*)&xs[r][c] = make_ushort4(f2bf(v.x), f2bf(v.y), f2bf(v.z), f2bf(v.w));
        }
        // stage W tile (64 rows x 128 k), bf16 copy
        #pragma unroll
        for (int i = 0; i < 8; ++i) {
            int f = (i * 256 + tid) * 8;
            int r = f >> 7;
            int c = f & 127;
            *(uint4*)&wsx[r][c] = *(const uint4*)(wb + (size_t)(bn + r) * DD + k0 + c);
        }
        __syncthreads();
        #pragma unroll
        for (int kk = 0; kk < 4; ++kk) {
            const int koff = kk * 32 + lhi * 8;
            s16x8 a[4], b[2];
            #pragma unroll
            for (int m = 0; m < 4; ++m)
                a[m] = *(const s16x8*)&xs[wr * 64 + m * 16 + l15][koff];
            #pragma unroll
            for (int n = 0; n < 2; ++n)
                b[n] = *(const s16x8*)&wsx[wc * 32 + n * 16 + l15][koff];
            #pragma unroll
            for (int m = 0; m < 4; ++m)
                #pragma unroll
                for (int n = 0; n < 2; ++n)
                    acc[m][n] = __builtin_amdgcn_mfma_f32_16x16x32_bf16(a[m], b[n], acc[m][n], 0, 0, 0);
        }
        __syncthreads();
    }
    // D layout: col = lane&15, row = (lane>>4)*4 + reg  [m89-verified]
    #pragma unroll
    for (int m = 0; m < 4; ++m)
        #pragma unroll
        for (int n = 0; n < 2; ++n)
            #pragma unroll
            for (int r = 0; r < 4; ++r) {
                int row = bm + wr * 64 + m * 16 + lhi * 4 + r;
                int col = bn + wc * 32 + n * 16 + l15;
                if (row < N_NODES) h[(size_t)row * DD + col] = f2bf(acc[m][n][r]);
            }
}

// ---------------- edge histogram ----------------
__global__ void hist_kernel(const int* __restrict__ row, int* __restrict__ counts)
{
    int i = blockIdx.x * blockDim.x + threadIdx.x;
    if (i < N_EDGES) atomicAdd(&counts[row[i]], 1);
}

// ---------------- 2-level exclusive scan ----------------
#define SCAN_B 512

__global__ void scan1_kernel(const int* __restrict__ counts, int* __restrict__ bsum)
{
    __shared__ int lds[SCAN_B];
    int i = blockIdx.x * SCAN_B + threadIdx.x;
    int v = (i < N_NODES) ? counts[i] : 0;
    lds[threadIdx.x] = v;
    __syncthreads();
    for (int s = SCAN_B / 2; s > 0; s >>= 1) {
        if (threadIdx.x < s) lds[threadIdx.x] += lds[threadIdx.x + s];
        __syncthreads();
    }
    if (threadIdx.x == 0) bsum[blockIdx.x] = lds[0];
}

__global__ void scan2_kernel(int* __restrict__ bsum, int nb)
{
    __shared__ int lds[SCAN_B];
    int tid = threadIdx.x;
    int v = (tid < nb) ? bsum[tid] : 0;
    lds[tid] = v;
    __syncthreads();
    for (int s = 1; s < SCAN_B; s <<= 1) {
        int t = (tid >= s) ? lds[tid - s] : 0;
        __syncthreads();
        lds[tid] += t;
        __syncthreads();
    }
    if (tid < nb) bsum[tid] = lds[tid] - v;  // exclusive
}

__global__ void scan3_kernel(const int* __restrict__ counts, const int* __restrict__ bsum,
                             int* __restrict__ row_start, int* __restrict__ cursor)
{
    __shared__ int lds[SCAN_B];
    int tid = threadIdx.x;
    int i = blockIdx.x * SCAN_B + tid;
    int v = (i < N_NODES) ? counts[i] : 0;
    lds[tid] = v;
    __syncthreads();
    for (int s = 1; s < SCAN_B; s <<= 1) {
        int t = (tid >= s) ? lds[tid - s] : 0;
        __syncthreads();
        lds[tid] += t;
        __syncthreads();
    }
    int excl = lds[tid] - v + bsum[blockIdx.x];
    if (i < N_NODES) { row_start[i] = excl; cursor[i] = excl; }
    if (i == N_NODES - 1) row_start[N_NODES] = excl + v;
}

// ---------------- scatter edges into CSR order, packed (col,val) ----------------
__global__ void scatter_kernel(const int* __restrict__ row, const int* __restrict__ col,
                               const float* __restrict__ val, int* __restrict__ cursor,
                               int2* __restrict__ pairs)
{
    int i = blockIdx.x * blockDim.x + threadIdx.x;
    if (i < N_EDGES) {
        int p = atomicAdd(&cursor[row[i]], 1);
        pairs[p] = make_int2(col[i], __float_as_int(val[i]));
    }
}

// ---------------- SpMM: one wave per row, bf16 h, shfl-broadcast edges ----------------
__global__ __launch_bounds__(256) void spmm_kernel(
    const ushort* __restrict__ h, const int2* __restrict__ pairs,
    const int* __restrict__ row_start, float* __restrict__ out)
{
    const int wid  = blockIdx.x * 4 + (threadIdx.x >> 6);
    const int lane = threadIdx.x & 63;
    if (wid >= N_NODES) return;
    const int s = row_start[wid];
    const int e = row_start[wid + 1];
    float ax = 0.f, ay = 0.f, az = 0.f, aw = 0.f;
    for (int base = s; base < e; base += 64) {
        const int n = min(64, e - base);
        int2 p = make_int2(0, 0);
        if (base + lane < e) p = pairs[base + lane];
        const int mycol = p.x;
        const int myval = p.y;
        for (int j = 0; j < n; ++j) {
            const int cidx = __shfl(mycol, j);
            const float v = __uint_as_float((unsigned)__shfl(myval, j));
            const ushort4 hv = *(const ushort4*)(h + (size_t)cidx * DD + lane * 4);
            ax += v * bf2f(hv.x);
            ay += v * bf2f(hv.y);
            az += v * bf2f(hv.z);
            aw += v * bf2f(hv.w);
        }
    }
    *(float4*)(out + (size_t)wid * DD + lane * 4) = make_float4(ax, ay, az, aw);
}

extern "C" void kernel_launch(void* const* d_in, const int* in_sizes, int n_in,
                              void* d_out, int out_size, void* d_ws, size_t ws_size,
                              hipStream_t stream)
{
    const float* x        = (const float*)d_in[0];
    const float* W        = (const float*)d_in[1];
    const float* edge_val = (const float*)d_in[2];
    const int*   edge_row = (const int*)d_in[3];
    const int*   edge_col = (const int*)d_in[4];
    float* out = (float*)d_out;

    char* ws = (char*)d_ws;
    size_t off = 0;
    auto alloc = [&](size_t bytes) {
        void* p = ws + off;
        off = (off + bytes + 255) & ~(size_t)255;
        return p;
    };
    ushort* h         = (ushort*)alloc((size_t)N_NODES * DD * sizeof(ushort)); // 51.2 MB
    int2*   pairs     = (int2*)  alloc((size_t)N_EDGES * sizeof(int2));        // 25.6 MB
    ushort* wb        = (ushort*)alloc((size_t)DD * DD * sizeof(ushort));      // 128 KB
    int*    counts    = (int*)   alloc((size_t)N_NODES * sizeof(int));
    int*    row_start = (int*)   alloc((size_t)(N_NODES + 1) * sizeof(int));
    int*    cursor    = (int*)   alloc((size_t)N_NODES * sizeof(int));
    int*    bsum      = (int*)   alloc(SCAN_B * sizeof(int));
    (void)ws_size;

    hipMemsetAsync(counts, 0, (size_t)N_NODES * sizeof(int), stream);

    // W -> bf16
    wconv_kernel<<<(DD * DD / 4) / 256, 256, 0, stream>>>(W, wb);

    // h = bf16(x @ W^T)
    dim3 ggrid((N_NODES + GBM - 1) / GBM, DD / GBN);
    gemm_mfma<<<ggrid, 256, 0, stream>>>(x, wb, h);

    // build CSR
    hist_kernel<<<(N_EDGES + 255) / 256, 256, 0, stream>>>(edge_row, counts);
    int nb = (N_NODES + SCAN_B - 1) / SCAN_B;  // 196
    scan1_kernel<<<nb, SCAN_B, 0, stream>>>(counts, bsum);
    scan2_kernel<<<1, SCAN_B, 0, stream>>>(bsum, nb);
    scan3_kernel<<<nb, SCAN_B, 0, stream>>>(counts, bsum, row_start, cursor);
    scatter_kernel<<<(N_EDGES + 255) / 256, 256, 0, stream>>>(edge_row, edge_col, edge_val,
                                                              cursor, pairs);

    // out[r] = sum val * h[col]
    int spmm_blocks = (N_NODES + 3) / 4;  // one wave per row
    spmm_kernel<<<spmm_blocks, 256, 0, stream>>>(h, pairs, row_start, out);
}

// Round 3
// 422.553 us; speedup vs baseline: 2.2928x; 1.5264x over previous
//
#include <hip/hip_runtime.h>

typedef float  f32x4 __attribute__((ext_vector_type(4)));
typedef short  s16x8 __attribute__((ext_vector_type(8)));

#define N_NODES 100000
#define N_EDGES 3200000
#define DD 256

#define ROWS_PER_BKT 128
#define NBKT 782           // ceil(100000/128), 782*128 = 100096
#define ACHUNK 4096
#define NABLK 782          // ceil(3.2M/4096)

__device__ __forceinline__ ushort f2bf(float f) {
    unsigned u = __float_as_uint(f);
    unsigned r = (u + 0x7FFFu + ((u >> 16) & 1u)) >> 16;  // RNE
    return (ushort)r;
}
__device__ __forceinline__ float bf2f(ushort u) {
    return __uint_as_float(((unsigned)u) << 16);
}

// ---------------- W fp32 -> bf16 ----------------
__global__ void wconv_kernel(const float* __restrict__ w, ushort* __restrict__ wb)
{
    int i = blockIdx.x * blockDim.x + threadIdx.x;
    float4 v = ((const float4*)w)[i];
    ((ushort4*)wb)[i] = make_ushort4(f2bf(v.x), f2bf(v.y), f2bf(v.z), f2bf(v.w));
}

// ---------------- GEMM: h(bf16) = x @ W^T via MFMA bf16 ----------------
#define GBM 128
#define GBN 64
#define LDX 136

__global__ __launch_bounds__(256) void gemm_mfma(
    const float* __restrict__ x, const ushort* __restrict__ wb, ushort* __restrict__ h)
{
    __shared__ ushort xs[GBM][LDX];
    __shared__ ushort wsx[GBN][LDX];
    const int tid  = threadIdx.x;
    const int lane = tid & 63;
    const int wave = tid >> 6;
    const int wr = wave >> 1, wc = wave & 1;
    const int bm = blockIdx.x * GBM;
    const int bn = blockIdx.y * GBN;
    const int l15 = lane & 15;
    const int lhi = lane >> 4;
    f32x4 acc[4][2] = {};

    for (int k0 = 0; k0 < DD; k0 += 128) {
        #pragma unroll
        for (int i = 0; i < 16; ++i) {
            int f = (i * 256 + tid) * 4;
            int r = f >> 7;
            int c = f & 127;
            float4 v = make_float4(0.f, 0.f, 0.f, 0.f);
            if (bm + r < N_NODES) v = *(const float4*)(x + (size_t)(bm + r) * DD + k0 + c);
            *(ushort4*)&xs[r][c] = make_ushort4(f2bf(v.x), f2bf(v.y), f2bf(v.z), f2bf(v.w));
        }
        #pragma unroll
        for (int i = 0; i < 8; ++i) {
            int f = (i * 256 + tid) * 8;
            int r = f >> 7;
            int c = f & 127;
            *(uint4*)&wsx[r][c] = *(const uint4*)(wb + (size_t)(bn + r) * DD + k0 + c);
        }
        __syncthreads();
        #pragma unroll
        for (int kk = 0; kk < 4; ++kk) {
            const int koff = kk * 32 + lhi * 8;
            s16x8 a[4], b[2];
            #pragma unroll
            for (int m = 0; m < 4; ++m)
                a[m] = *(const s16x8*)&xs[wr * 64 + m * 16 + l15][koff];
            #pragma unroll
            for (int n = 0; n < 2; ++n)
                b[n] = *(const s16x8*)&wsx[wc * 32 + n * 16 + l15][koff];
            #pragma unroll
            for (int m = 0; m < 4; ++m)
                #pragma unroll
                for (int n = 0; n < 2; ++n)
                    acc[m][n] = __builtin_amdgcn_mfma_f32_16x16x32_bf16(a[m], b[n], acc[m][n], 0, 0, 0);
        }
        __syncthreads();
    }
    #pragma unroll
    for (int m = 0; m < 4; ++m)
        #pragma unroll
        for (int n = 0; n < 2; ++n)
            #pragma unroll
            for (int r = 0; r < 4; ++r) {
                int row = bm + wr * 64 + m * 16 + lhi * 4 + r;
                int col = bn + wc * 32 + n * 16 + l15;
                if (row < N_NODES) h[(size_t)row * DD + col] = f2bf(acc[m][n][r]);
            }
}

// ---------------- coarse histogram (782 buckets) ----------------
__global__ __launch_bounds__(256) void coarse_hist(const int* __restrict__ erow, int* __restrict__ bcnt)
{
    __shared__ int h[NBKT];
    for (int i = threadIdx.x; i < NBKT; i += 256) h[i] = 0;
    __syncthreads();
    const int base = blockIdx.x * ACHUNK;
    #pragma unroll
    for (int k = 0; k < 16; ++k) {
        int i = base + k * 256 + threadIdx.x;
        if (i < N_EDGES) atomicAdd(&h[erow[i] >> 7], 1);
    }
    __syncthreads();
    for (int i = threadIdx.x; i < NBKT; i += 256)
        if (h[i]) atomicAdd(&bcnt[i], h[i]);
}

// ---------------- exclusive scan over 782 bucket counts ----------------
__global__ __launch_bounds__(1024) void bucket_scan(const int* __restrict__ bcnt, int* __restrict__ bbase,
                                                    int* __restrict__ gcur, int* __restrict__ row_start)
{
    __shared__ int lds[1024];
    const int tid = threadIdx.x;
    int v = (tid < NBKT) ? bcnt[tid] : 0;
    lds[tid] = v;
    __syncthreads();
    for (int s = 1; s < 1024; s <<= 1) {
        int t = (tid >= s) ? lds[tid - s] : 0;
        __syncthreads();
        lds[tid] += t;
        __syncthreads();
    }
    int excl = lds[tid] - v;
    if (tid < NBKT) { bbase[tid] = excl; gcur[tid] = excl; }
    if (tid == NBKT - 1) bbase[NBKT] = excl + v;
    if (tid == 0) row_start[N_NODES] = N_EDGES;
}

// ---------------- pass A: coarse partition, LDS-staged coalesced run writes ----------------
__global__ __launch_bounds__(256) void passA(const int* __restrict__ erow, const int* __restrict__ ecol,
                                             const float* __restrict__ eval, int* __restrict__ gcur,
                                             int2* __restrict__ pairsA)
{
    __shared__ int hist[NBKT];
    __shared__ int sbase[NBKT];
    __shared__ int scur[NBKT];
    __shared__ int rbase[NBKT];
    __shared__ int gsum[256];
    __shared__ int2 staged[ACHUNK];
    __shared__ int gdst[ACHUNK];
    const int tid = threadIdx.x;
    for (int i = tid; i < NBKT; i += 256) hist[i] = 0;
    __syncthreads();
    const int base = blockIdx.x * ACHUNK;
    int pk[16]; float vv[16]; int bk[16];
    #pragma unroll
    for (int k = 0; k < 16; ++k) {
        int i = base + k * 256 + tid;
        bk[k] = -1;
        if (i < N_EDGES) {
            int r = erow[i];
            bk[k] = r >> 7;
            pk[k] = ecol[i] | ((r & 127) << 17);
            vv[k] = eval[i];
            atomicAdd(&hist[bk[k]], 1);
        }
    }
    __syncthreads();
    // block-level exclusive scan of hist (256 threads x 4 bins)
    int gs = 0, lv[4];
    #pragma unroll
    for (int j = 0; j < 4; ++j) {
        int b = tid * 4 + j;
        lv[j] = (b < NBKT) ? hist[b] : 0;
        gs += lv[j];
    }
    gsum[tid] = gs;
    __syncthreads();
    for (int s = 1; s < 256; s <<= 1) {
        int t = (tid >= s) ? gsum[tid - s] : 0;
        __syncthreads();
        gsum[tid] += t;
        __syncthreads();
    }
    int run = gsum[tid] - gs;
    #pragma unroll
    for (int j = 0; j < 4; ++j) {
        int b = tid * 4 + j;
        if (b < NBKT) { sbase[b] = run; scur[b] = run; }
        run += lv[j];
    }
    __syncthreads();
    // reserve global run space (one atomic per present bucket per block)
    for (int b = tid; b < NBKT; b += 256) {
        int c = hist[b];
        if (c) rbase[b] = atomicAdd(&gcur[b], c);
    }
    __syncthreads();
    // place edges into LDS staging, bucket-sorted; record global dest
    #pragma unroll
    for (int k = 0; k < 16; ++k) {
        if (bk[k] >= 0) {
            int lo = atomicAdd(&scur[bk[k]], 1);
            staged[lo] = make_int2(pk[k], __float_as_int(vv[k]));
            gdst[lo] = rbase[bk[k]] + (lo - sbase[bk[k]]);
        }
    }
    __syncthreads();
    const int cnt = min(ACHUNK, N_EDGES - base);
    for (int t = tid; t < cnt; t += 256)
        pairsA[gdst[t]] = staged[t];
}

// ---------------- pass B: exact sort within bucket (L2-resident window) ----------------
__global__ __launch_bounds__(256) void passB(const int2* __restrict__ pairsA, const int* __restrict__ bbase,
                                             int2* __restrict__ pairsB, int* __restrict__ row_start)
{
    __shared__ int hist[ROWS_PER_BKT];
    __shared__ int lds[256];
    __shared__ int cur[ROWS_PER_BKT];
    const int tid = threadIdx.x;
    const int b = blockIdx.x;
    const int s = bbase[b], e = bbase[b + 1];
    if (tid < ROWS_PER_BKT) hist[tid] = 0;
    __syncthreads();
    for (int i = s + tid; i < e; i += 256)
        atomicAdd(&hist[(pairsA[i].x >> 17) & 127], 1);
    __syncthreads();
    int v = (tid < ROWS_PER_BKT) ? hist[tid] : 0;
    lds[tid] = v;
    __syncthreads();
    for (int st = 1; st < ROWS_PER_BKT; st <<= 1) {
        int t = (tid >= st && tid < ROWS_PER_BKT) ? lds[tid - st] : 0;
        __syncthreads();
        if (tid < ROWS_PER_BKT) lds[tid] += t;
        __syncthreads();
    }
    if (tid < ROWS_PER_BKT) {
        int excl = lds[tid] - v;
        int r = b * ROWS_PER_BKT + tid;
        if (r < N_NODES) row_start[r] = s + excl;
        cur[tid] = s + excl;
    }
    __syncthreads();
    for (int i = s + tid; i < e; i += 256) {
        int2 p = pairsA[i];
        int rl = (p.x >> 17) & 127;
        int d = atomicAdd(&cur[rl], 1);
        pairsB[d] = make_int2(p.x & 0x1FFFF, p.y);
    }
}

// ---------------- SpMM: one wave per row, bf16 h, shfl-broadcast edges ----------------
__global__ __launch_bounds__(256) void spmm_kernel(
    const ushort* __restrict__ h, const int2* __restrict__ pairs,
    const int* __restrict__ row_start, float* __restrict__ out)
{
    const int wid  = blockIdx.x * 4 + (threadIdx.x >> 6);
    const int lane = threadIdx.x & 63;
    if (wid >= N_NODES) return;
    const int s = row_start[wid];
    const int e = row_start[wid + 1];
    float ax = 0.f, ay = 0.f, az = 0.f, aw = 0.f;
    for (int base = s; base < e; base += 64) {
        const int n = min(64, e - base);
        int2 p = make_int2(0, 0);
        if (base + lane < e) p = pairs[base + lane];
        const int mycol = p.x;
        const int myval = p.y;
        for (int j = 0; j < n; ++j) {
            const int cidx = __shfl(mycol, j);
            const float v = __uint_as_float((unsigned)__shfl(myval, j));
            const ushort4 hv = *(const ushort4*)(h + (size_t)cidx * DD + lane * 4);
            ax += v * bf2f(hv.x);
            ay += v * bf2f(hv.y);
            az += v * bf2f(hv.z);
            aw += v * bf2f(hv.w);
        }
    }
    *(float4*)(out + (size_t)wid * DD + lane * 4) = make_float4(ax, ay, az, aw);
}

extern "C" void kernel_launch(void* const* d_in, const int* in_sizes, int n_in,
                              void* d_out, int out_size, void* d_ws, size_t ws_size,
                              hipStream_t stream)
{
    const float* x        = (const float*)d_in[0];
    const float* W        = (const float*)d_in[1];
    const float* edge_val = (const float*)d_in[2];
    const int*   edge_row = (const int*)d_in[3];
    const int*   edge_col = (const int*)d_in[4];
    float* out = (float*)d_out;

    char* ws = (char*)d_ws;
    size_t off = 0;
    auto alloc = [&](size_t bytes) {
        void* p = ws + off;
        off = (off + bytes + 255) & ~(size_t)255;
        return p;
    };
    ushort* h         = (ushort*)alloc((size_t)N_NODES * DD * sizeof(ushort)); // 51.2 MB
    int2*   pairsA    = (int2*)  alloc((size_t)N_EDGES * sizeof(int2));        // 25.6 MB
    int2*   pairsB    = (int2*)  alloc((size_t)N_EDGES * sizeof(int2));        // 25.6 MB
    ushort* wb        = (ushort*)alloc((size_t)DD * DD * sizeof(ushort));
    int*    bcnt      = (int*)   alloc((size_t)NBKT * sizeof(int));
    int*    bbase     = (int*)   alloc((size_t)(NBKT + 1) * sizeof(int));
    int*    gcur      = (int*)   alloc((size_t)NBKT * sizeof(int));
    int*    row_start = (int*)   alloc((size_t)(N_NODES + 1) * sizeof(int));
    (void)ws_size;

    hipMemsetAsync(bcnt, 0, (size_t)NBKT * sizeof(int), stream);

    wconv_kernel<<<(DD * DD / 4) / 256, 256, 0, stream>>>(W, wb);

    dim3 ggrid((N_NODES + GBM - 1) / GBM, DD / GBN);
    gemm_mfma<<<ggrid, 256, 0, stream>>>(x, wb, h);

    coarse_hist<<<NABLK, 256, 0, stream>>>(edge_row, bcnt);
    bucket_scan<<<1, 1024, 0, stream>>>(bcnt, bbase, gcur, row_start);
    passA<<<NABLK, 256, 0, stream>>>(edge_row, edge_col, edge_val, gcur, pairsA);
    passB<<<NBKT, 256, 0, stream>>>(pairsA, bbase, pairsB, row_start);

    int spmm_blocks = (N_NODES + 3) / 4;
    spmm_kernel<<<spmm_blocks, 256, 0, stream>>>(h, pairsB, row_start, out);
}

// Round 4
// 418.298 us; speedup vs baseline: 2.3161x; 1.0102x over previous
//
#include <hip/hip_runtime.h>

typedef float  f32x4 __attribute__((ext_vector_type(4)));
typedef short  s16x8 __attribute__((ext_vector_type(8)));

#define N_NODES 100000
#define N_EDGES 3200000
#define DD 256

#define ROWS_PER_BKT 128
#define NBKT 782           // ceil(100000/128)
#define ACHUNK 4096
#define NABLK 782          // ceil(3.2M/4096)

__device__ __forceinline__ ushort f2bf(float f) {
    unsigned u = __float_as_uint(f);
    unsigned r = (u + 0x7FFFu + ((u >> 16) & 1u)) >> 16;  // RNE
    return (ushort)r;
}
__device__ __forceinline__ float bf2f(ushort u) {
    return __uint_as_float(((unsigned)u) << 16);
}

// ---------------- W fp32 -> bf16 ----------------
__global__ void wconv_kernel(const float* __restrict__ w, ushort* __restrict__ wb)
{
    int i = blockIdx.x * blockDim.x + threadIdx.x;
    float4 v = ((const float4*)w)[i];
    ((ushort4*)wb)[i] = make_ushort4(f2bf(v.x), f2bf(v.y), f2bf(v.z), f2bf(v.w));
}

// ---------------- GEMM: h(bf16) = x @ W^T via MFMA bf16 ----------------
#define GBM 128
#define GBN 64
#define LDX 136

__global__ __launch_bounds__(256) void gemm_mfma(
    const float* __restrict__ x, const ushort* __restrict__ wb, ushort* __restrict__ h)
{
    __shared__ ushort xs[GBM][LDX];
    __shared__ ushort wsx[GBN][LDX];
    const int tid  = threadIdx.x;
    const int lane = tid & 63;
    const int wave = tid >> 6;
    const int wr = wave >> 1, wc = wave & 1;
    const int bm = blockIdx.x * GBM;
    const int bn = blockIdx.y * GBN;
    const int l15 = lane & 15;
    const int lhi = lane >> 4;
    f32x4 acc[4][2] = {};

    for (int k0 = 0; k0 < DD; k0 += 128) {
        #pragma unroll
        for (int i = 0; i < 16; ++i) {
            int f = (i * 256 + tid) * 4;
            int r = f >> 7;
            int c = f & 127;
            float4 v = make_float4(0.f, 0.f, 0.f, 0.f);
            if (bm + r < N_NODES) v = *(const float4*)(x + (size_t)(bm + r) * DD + k0 + c);
            *(ushort4*)&xs[r][c] = make_ushort4(f2bf(v.x), f2bf(v.y), f2bf(v.z), f2bf(v.w));
        }
        #pragma unroll
        for (int i = 0; i < 8; ++i) {
            int f = (i * 256 + tid) * 8;
            int r = f >> 7;
            int c = f & 127;
            *(uint4*)&wsx[r][c] = *(const uint4*)(wb + (size_t)(bn + r) * DD + k0 + c);
        }
        __syncthreads();
        #pragma unroll
        for (int kk = 0; kk < 4; ++kk) {
            const int koff = kk * 32 + lhi * 8;
            s16x8 a[4], b[2];
            #pragma unroll
            for (int m = 0; m < 4; ++m)
                a[m] = *(const s16x8*)&xs[wr * 64 + m * 16 + l15][koff];
            #pragma unroll
            for (int n = 0; n < 2; ++n)
                b[n] = *(const s16x8*)&wsx[wc * 32 + n * 16 + l15][koff];
            #pragma unroll
            for (int m = 0; m < 4; ++m)
                #pragma unroll
                for (int n = 0; n < 2; ++n)
                    acc[m][n] = __builtin_amdgcn_mfma_f32_16x16x32_bf16(a[m], b[n], acc[m][n], 0, 0, 0);
        }
        __syncthreads();
    }
    #pragma unroll
    for (int m = 0; m < 4; ++m)
        #pragma unroll
        for (int n = 0; n < 2; ++n)
            #pragma unroll
            for (int r = 0; r < 4; ++r) {
                int row = bm + wr * 64 + m * 16 + lhi * 4 + r;
                int col = bn + wc * 32 + n * 16 + l15;
                if (row < N_NODES) h[(size_t)row * DD + col] = f2bf(acc[m][n][r]);
            }
}

// ---------------- coarse histogram (782 buckets) ----------------
__global__ __launch_bounds__(256) void coarse_hist(const int* __restrict__ erow, int* __restrict__ bcnt)
{
    __shared__ int h[NBKT];
    for (int i = threadIdx.x; i < NBKT; i += 256) h[i] = 0;
    __syncthreads();
    const int base = blockIdx.x * ACHUNK;
    #pragma unroll
    for (int k = 0; k < 16; ++k) {
        int i = base + k * 256 + threadIdx.x;
        if (i < N_EDGES) atomicAdd(&h[erow[i] >> 7], 1);
    }
    __syncthreads();
    for (int i = threadIdx.x; i < NBKT; i += 256)
        if (h[i]) atomicAdd(&bcnt[i], h[i]);
}

// ---------------- exclusive scan over 782 bucket counts ----------------
__global__ __launch_bounds__(1024) void bucket_scan(const int* __restrict__ bcnt, int* __restrict__ bbase,
                                                    int* __restrict__ gcur, int* __restrict__ row_start)
{
    __shared__ int lds[1024];
    const int tid = threadIdx.x;
    int v = (tid < NBKT) ? bcnt[tid] : 0;
    lds[tid] = v;
    __syncthreads();
    for (int s = 1; s < 1024; s <<= 1) {
        int t = (tid >= s) ? lds[tid - s] : 0;
        __syncthreads();
        lds[tid] += t;
        __syncthreads();
    }
    int excl = lds[tid] - v;
    if (tid < NBKT) { bbase[tid] = excl; gcur[tid] = excl; }
    if (tid == NBKT - 1) bbase[NBKT] = excl + v;
    if (tid == 0) row_start[N_NODES] = N_EDGES;
}

// ---------------- pass A: coarse partition, LDS-staged coalesced run writes ----------------
__global__ __launch_bounds__(256) void passA(const int* __restrict__ erow, const int* __restrict__ ecol,
                                             const float* __restrict__ eval, int* __restrict__ gcur,
                                             int2* __restrict__ pairsA)
{
    __shared__ int hist[NBKT];
    __shared__ int sbase[NBKT];
    __shared__ int scur[NBKT];
    __shared__ int rbase[NBKT];
    __shared__ int gsum[256];
    __shared__ int2 staged[ACHUNK];
    __shared__ int gdst[ACHUNK];
    const int tid = threadIdx.x;
    for (int i = tid; i < NBKT; i += 256) hist[i] = 0;
    __syncthreads();
    const int base = blockIdx.x * ACHUNK;
    int pk[16]; float vv[16]; int bk[16];
    #pragma unroll
    for (int k = 0; k < 16; ++k) {
        int i = base + k * 256 + tid;
        bk[k] = -1;
        if (i < N_EDGES) {
            int r = erow[i];
            bk[k] = r >> 7;
            pk[k] = ecol[i] | ((r & 127) << 17);
            vv[k] = eval[i];
            atomicAdd(&hist[bk[k]], 1);
        }
    }
    __syncthreads();
    int gs = 0, lv[4];
    #pragma unroll
    for (int j = 0; j < 4; ++j) {
        int b = tid * 4 + j;
        lv[j] = (b < NBKT) ? hist[b] : 0;
        gs += lv[j];
    }
    gsum[tid] = gs;
    __syncthreads();
    for (int s = 1; s < 256; s <<= 1) {
        int t = (tid >= s) ? gsum[tid - s] : 0;
        __syncthreads();
        gsum[tid] += t;
        __syncthreads();
    }
    int run = gsum[tid] - gs;
    #pragma unroll
    for (int j = 0; j < 4; ++j) {
        int b = tid * 4 + j;
        if (b < NBKT) { sbase[b] = run; scur[b] = run; }
        run += lv[j];
    }
    __syncthreads();
    for (int b = tid; b < NBKT; b += 256) {
        int c = hist[b];
        if (c) rbase[b] = atomicAdd(&gcur[b], c);
    }
    __syncthreads();
    #pragma unroll
    for (int k = 0; k < 16; ++k) {
        if (bk[k] >= 0) {
            int lo = atomicAdd(&scur[bk[k]], 1);
            staged[lo] = make_int2(pk[k], __float_as_int(vv[k]));
            gdst[lo] = rbase[bk[k]] + (lo - sbase[bk[k]]);
        }
    }
    __syncthreads();
    const int cnt = min(ACHUNK, N_EDGES - base);
    for (int t = tid; t < cnt; t += 256)
        pairsA[gdst[t]] = staged[t];
}

// ---------------- pass B: exact sort within bucket ----------------
__global__ __launch_bounds__(256) void passB(const int2* __restrict__ pairsA, const int* __restrict__ bbase,
                                             int2* __restrict__ pairsB, int* __restrict__ row_start)
{
    __shared__ int hist[ROWS_PER_BKT];
    __shared__ int lds[256];
    __shared__ int cur[ROWS_PER_BKT];
    const int tid = threadIdx.x;
    const int b = blockIdx.x;
    const int s = bbase[b], e = bbase[b + 1];
    if (tid < ROWS_PER_BKT) hist[tid] = 0;
    __syncthreads();
    for (int i = s + tid; i < e; i += 256)
        atomicAdd(&hist[(pairsA[i].x >> 17) & 127], 1);
    __syncthreads();
    int v = (tid < ROWS_PER_BKT) ? hist[tid] : 0;
    lds[tid] = v;
    __syncthreads();
    for (int st = 1; st < ROWS_PER_BKT; st <<= 1) {
        int t = (tid >= st && tid < ROWS_PER_BKT) ? lds[tid - st] : 0;
        __syncthreads();
        if (tid < ROWS_PER_BKT) lds[tid] += t;
        __syncthreads();
    }
    if (tid < ROWS_PER_BKT) {
        int excl = lds[tid] - v;
        int r = b * ROWS_PER_BKT + tid;
        if (r < N_NODES) row_start[r] = s + excl;
        cur[tid] = s + excl;
    }
    __syncthreads();
    for (int i = s + tid; i < e; i += 256) {
        int2 p = pairsA[i];
        int rl = (p.x >> 17) & 127;
        int d = atomicAdd(&cur[rl], 1);
        pairsB[d] = make_int2(p.x & 0x1FFFF, p.y);
    }
}

// ---------------- SpMM: one wave per row, 8-deep pipelined gathers ----------------
__global__ __launch_bounds__(256) void spmm_kernel(
    const ushort* __restrict__ h, const int2* __restrict__ pairs,
    const int* __restrict__ row_start, float* __restrict__ out)
{
    const int wid  = blockIdx.x * 4 + (threadIdx.x >> 6);
    const int lane = threadIdx.x & 63;
    if (wid >= N_NODES) return;
    const int s = row_start[wid];
    const int e = row_start[wid + 1];
    float ax = 0.f, ay = 0.f, az = 0.f, aw = 0.f;

    int2 p = make_int2(0, 0);
    if (s + lane < e) p = pairs[s + lane];

    for (int base = s; base < e; base += 64) {
        const int n = min(64, e - base);
        // prefetch next batch of edge pairs
        int2 pnext = make_int2(0, 0);
        if (base + 64 + lane < e) pnext = pairs[base + 64 + lane];

        int j = 0;
        for (; j + 8 <= n; j += 8) {
            int c[8]; float v[8];
            #pragma unroll
            for (int q = 0; q < 8; ++q) {
                c[q] = __shfl(p.x, j + q);
                v[q] = __uint_as_float((unsigned)__shfl(p.y, j + q));
            }
            ushort4 hv[8];
            #pragma unroll
            for (int q = 0; q < 8; ++q)
                hv[q] = *(const ushort4*)(h + (size_t)c[q] * DD + lane * 4);
            #pragma unroll
            for (int q = 0; q < 8; ++q) {
                ax += v[q] * bf2f(hv[q].x);
                ay += v[q] * bf2f(hv[q].y);
                az += v[q] * bf2f(hv[q].z);
                aw += v[q] * bf2f(hv[q].w);
            }
        }
        for (; j < n; ++j) {
            const int cidx = __shfl(p.x, j);
            const float v = __uint_as_float((unsigned)__shfl(p.y, j));
            const ushort4 hv = *(const ushort4*)(h + (size_t)cidx * DD + lane * 4);
            ax += v * bf2f(hv.x);
            ay += v * bf2f(hv.y);
            az += v * bf2f(hv.z);
            aw += v * bf2f(hv.w);
        }
        p = pnext;
    }
    *(float4*)(out + (size_t)wid * DD + lane * 4) = make_float4(ax, ay, az, aw);
}

extern "C" void kernel_launch(void* const* d_in, const int* in_sizes, int n_in,
                              void* d_out, int out_size, void* d_ws, size_t ws_size,
                              hipStream_t stream)
{
    const float* x        = (const float*)d_in[0];
    const float* W        = (const float*)d_in[1];
    const float* edge_val = (const float*)d_in[2];
    const int*   edge_row = (const int*)d_in[3];
    const int*   edge_col = (const int*)d_in[4];
    float* out = (float*)d_out;

    char* ws = (char*)d_ws;
    size_t off = 0;
    auto alloc = [&](size_t bytes) {
        void* p = ws + off;
        off = (off + bytes + 255) & ~(size_t)255;
        return p;
    };
    ushort* h         = (ushort*)alloc((size_t)N_NODES * DD * sizeof(ushort)); // 51.2 MB
    int2*   pairsA    = (int2*)  alloc((size_t)N_EDGES * sizeof(int2));        // 25.6 MB
    int2*   pairsB    = (int2*)  alloc((size_t)N_EDGES * sizeof(int2));        // 25.6 MB
    ushort* wb        = (ushort*)alloc((size_t)DD * DD * sizeof(ushort));
    int*    bcnt      = (int*)   alloc((size_t)NBKT * sizeof(int));
    int*    bbase     = (int*)   alloc((size_t)(NBKT + 1) * sizeof(int));
    int*    gcur      = (int*)   alloc((size_t)NBKT * sizeof(int));
    int*    row_start = (int*)   alloc((size_t)(N_NODES + 1) * sizeof(int));
    (void)ws_size;

    hipMemsetAsync(bcnt, 0, (size_t)NBKT * sizeof(int), stream);

    wconv_kernel<<<(DD * DD / 4) / 256, 256, 0, stream>>>(W, wb);

    dim3 ggrid((N_NODES + GBM - 1) / GBM, DD / GBN);
    gemm_mfma<<<ggrid, 256, 0, stream>>>(x, wb, h);

    coarse_hist<<<NABLK, 256, 0, stream>>>(edge_row, bcnt);
    bucket_scan<<<1, 1024, 0, stream>>>(bcnt, bbase, gcur, row_start);
    passA<<<NABLK, 256, 0, stream>>>(edge_row, edge_col, edge_val, gcur, pairsA);
    passB<<<NBKT, 256, 0, stream>>>(pairsA, bbase, pairsB, row_start);

    int spmm_blocks = (N_NODES + 3) / 4;
    spmm_kernel<<<spmm_blocks, 256, 0, stream>>>(h, pairsB, row_start, out);
}

// Round 5
// 413.434 us; speedup vs baseline: 2.3434x; 1.0118x over previous
//
#include <hip/hip_runtime.h>
#include <hip/hip_bf16.h>

typedef float  f32x4 __attribute__((ext_vector_type(4)));
typedef short  s16x8 __attribute__((ext_vector_type(8)));

#define N_NODES 100000
#define N_EDGES 3200000
#define DD 256

#define ROWS_PER_BKT 128
#define NBKT 782           // ceil(100000/128)
#define ACHUNK 4096
#define NABLK 782          // ceil(3.2M/4096)

__device__ __forceinline__ ushort f2bf(float f) {
    union { __hip_bfloat16 b; ushort u; } cv;
    cv.b = __float2bfloat16(f);
    return cv.u;
}
__device__ __forceinline__ float bf2f(ushort u) {
    return __uint_as_float(((unsigned)u) << 16);
}

// ---------------- W fp32 -> bf16 ----------------
__global__ void wconv_kernel(const float* __restrict__ w, ushort* __restrict__ wb)
{
    int i = blockIdx.x * blockDim.x + threadIdx.x;
    float4 v = ((const float4*)w)[i];
    ((ushort4*)wb)[i] = make_ushort4(f2bf(v.x), f2bf(v.y), f2bf(v.z), f2bf(v.w));
}

// ---------------- GEMM: h(bf16) = x @ W^T via MFMA bf16 ----------------
#define GBM 128
#define GBN 64
#define LDX 136

__global__ __launch_bounds__(256) void gemm_mfma(
    const float* __restrict__ x, const ushort* __restrict__ wb, ushort* __restrict__ h)
{
    __shared__ ushort xs[GBM][LDX];
    __shared__ ushort wsx[GBN][LDX];
    const int tid  = threadIdx.x;
    const int lane = tid & 63;
    const int wave = tid >> 6;
    const int wr = wave >> 1, wc = wave & 1;
    const int bm = blockIdx.x * GBM;
    const int bn = blockIdx.y * GBN;
    const int l15 = lane & 15;
    const int lhi = lane >> 4;
    f32x4 acc[4][2] = {};

    for (int k0 = 0; k0 < DD; k0 += 128) {
        #pragma unroll
        for (int i = 0; i < 16; ++i) {
            int f = (i * 256 + tid) * 4;
            int r = f >> 7;
            int c = f & 127;
            float4 v = make_float4(0.f, 0.f, 0.f, 0.f);
            if (bm + r < N_NODES) v = *(const float4*)(x + (size_t)(bm + r) * DD + k0 + c);
            *(ushort4*)&xs[r][c] = make_ushort4(f2bf(v.x), f2bf(v.y), f2bf(v.z), f2bf(v.w));
        }
        #pragma unroll
        for (int i = 0; i < 8; ++i) {
            int f = (i * 256 + tid) * 8;
            int r = f >> 7;
            int c = f & 127;
            *(uint4*)&wsx[r][c] = *(const uint4*)(wb + (size_t)(bn + r) * DD + k0 + c);
        }
        __syncthreads();
        #pragma unroll
        for (int kk = 0; kk < 4; ++kk) {
            const int koff = kk * 32 + lhi * 8;
            s16x8 a[4], b[2];
            #pragma unroll
            for (int m = 0; m < 4; ++m)
                a[m] = *(const s16x8*)&xs[wr * 64 + m * 16 + l15][koff];
            #pragma unroll
            for (int n = 0; n < 2; ++n)
                b[n] = *(const s16x8*)&wsx[wc * 32 + n * 16 + l15][koff];
            #pragma unroll
            for (int m = 0; m < 4; ++m)
                #pragma unroll
                for (int n = 0; n < 2; ++n)
                    acc[m][n] = __builtin_amdgcn_mfma_f32_16x16x32_bf16(a[m], b[n], acc[m][n], 0, 0, 0);
        }
        __syncthreads();
    }
    #pragma unroll
    for (int m = 0; m < 4; ++m)
        #pragma unroll
        for (int n = 0; n < 2; ++n)
            #pragma unroll
            for (int r = 0; r < 4; ++r) {
                int row = bm + wr * 64 + m * 16 + lhi * 4 + r;
                int col = bn + wc * 32 + n * 16 + l15;
                if (row < N_NODES) h[(size_t)row * DD + col] = f2bf(acc[m][n][r]);
            }
}

// ---------------- coarse histogram (782 buckets) ----------------
__global__ __launch_bounds__(256) void coarse_hist(const int* __restrict__ erow, int* __restrict__ bcnt)
{
    __shared__ int h[NBKT];
    for (int i = threadIdx.x; i < NBKT; i += 256) h[i] = 0;
    __syncthreads();
    const int base = blockIdx.x * ACHUNK;
    #pragma unroll
    for (int k = 0; k < 16; ++k) {
        int i = base + k * 256 + threadIdx.x;
        if (i < N_EDGES) atomicAdd(&h[erow[i] >> 7], 1);
    }
    __syncthreads();
    for (int i = threadIdx.x; i < NBKT; i += 256)
        if (h[i]) atomicAdd(&bcnt[i], h[i]);
}

// ---------------- exclusive scan over 782 bucket counts ----------------
__global__ __launch_bounds__(1024) void bucket_scan(const int* __restrict__ bcnt, int* __restrict__ bbase,
                                                    int* __restrict__ gcur, int* __restrict__ row_start)
{
    __shared__ int lds[1024];
    const int tid = threadIdx.x;
    int v = (tid < NBKT) ? bcnt[tid] : 0;
    lds[tid] = v;
    __syncthreads();
    for (int s = 1; s < 1024; s <<= 1) {
        int t = (tid >= s) ? lds[tid - s] : 0;
        __syncthreads();
        lds[tid] += t;
        __syncthreads();
    }
    int excl = lds[tid] - v;
    if (tid < NBKT) { bbase[tid] = excl; gcur[tid] = excl; }
    if (tid == NBKT - 1) bbase[NBKT] = excl + v;
    if (tid == 0) row_start[N_NODES] = N_EDGES;
}

// ---------------- pass A: coarse partition, LDS-staged coalesced run writes ----------------
__global__ __launch_bounds__(256) void passA(const int* __restrict__ erow, const int* __restrict__ ecol,
                                             const float* __restrict__ eval, int* __restrict__ gcur,
                                             int2* __restrict__ pairsA)
{
    __shared__ int hist[NBKT];
    __shared__ int sbase[NBKT];
    __shared__ int scur[NBKT];
    __shared__ int rbase[NBKT];
    __shared__ int gsum[256];
    __shared__ int2 staged[ACHUNK];
    __shared__ int gdst[ACHUNK];
    const int tid = threadIdx.x;
    for (int i = tid; i < NBKT; i += 256) hist[i] = 0;
    __syncthreads();
    const int base = blockIdx.x * ACHUNK;
    int pk[16]; float vv[16]; int bk[16];
    #pragma unroll
    for (int k = 0; k < 16; ++k) {
        int i = base + k * 256 + tid;
        bk[k] = -1;
        if (i < N_EDGES) {
            int r = erow[i];
            bk[k] = r >> 7;
            pk[k] = ecol[i] | ((r & 127) << 17);
            vv[k] = eval[i];
            atomicAdd(&hist[bk[k]], 1);
        }
    }
    __syncthreads();
    int gs = 0, lv[4];
    #pragma unroll
    for (int j = 0; j < 4; ++j) {
        int b = tid * 4 + j;
        lv[j] = (b < NBKT) ? hist[b] : 0;
        gs += lv[j];
    }
    gsum[tid] = gs;
    __syncthreads();
    for (int s = 1; s < 256; s <<= 1) {
        int t = (tid >= s) ? gsum[tid - s] : 0;
        __syncthreads();
        gsum[tid] += t;
        __syncthreads();
    }
    int run = gsum[tid] - gs;
    #pragma unroll
    for (int j = 0; j < 4; ++j) {
        int b = tid * 4 + j;
        if (b < NBKT) { sbase[b] = run; scur[b] = run; }
        run += lv[j];
    }
    __syncthreads();
    for (int b = tid; b < NBKT; b += 256) {
        int c = hist[b];
        if (c) rbase[b] = atomicAdd(&gcur[b], c);
    }
    __syncthreads();
    #pragma unroll
    for (int k = 0; k < 16; ++k) {
        if (bk[k] >= 0) {
            int lo = atomicAdd(&scur[bk[k]], 1);
            staged[lo] = make_int2(pk[k], __float_as_int(vv[k]));
            gdst[lo] = rbase[bk[k]] + (lo - sbase[bk[k]]);
        }
    }
    __syncthreads();
    const int cnt = min(ACHUNK, N_EDGES - base);
    for (int t = tid; t < cnt; t += 256)
        pairsA[gdst[t]] = staged[t];
}

// ---------------- pass B: exact sort within bucket ----------------
__global__ __launch_bounds__(256) void passB(const int2* __restrict__ pairsA, const int* __restrict__ bbase,
                                             int2* __restrict__ pairsB, int* __restrict__ row_start)
{
    __shared__ int hist[ROWS_PER_BKT];
    __shared__ int lds[256];
    __shared__ int cur[ROWS_PER_BKT];
    const int tid = threadIdx.x;
    const int b = blockIdx.x;
    const int s = bbase[b], e = bbase[b + 1];
    if (tid < ROWS_PER_BKT) hist[tid] = 0;
    __syncthreads();
    for (int i = s + tid; i < e; i += 256)
        atomicAdd(&hist[(pairsA[i].x >> 17) & 127], 1);
    __syncthreads();
    int v = (tid < ROWS_PER_BKT) ? hist[tid] : 0;
    lds[tid] = v;
    __syncthreads();
    for (int st = 1; st < ROWS_PER_BKT; st <<= 1) {
        int t = (tid >= st && tid < ROWS_PER_BKT) ? lds[tid - st] : 0;
        __syncthreads();
        if (tid < ROWS_PER_BKT) lds[tid] += t;
        __syncthreads();
    }
    if (tid < ROWS_PER_BKT) {
        int excl = lds[tid] - v;
        int r = b * ROWS_PER_BKT + tid;
        if (r < N_NODES) row_start[r] = s + excl;
        cur[tid] = s + excl;
    }
    __syncthreads();
    for (int i = s + tid; i < e; i += 256) {
        int2 p = pairsA[i];
        int rl = (p.x >> 17) & 127;
        int d = atomicAdd(&cur[rl], 1);
        pairsB[d] = make_int2(p.x & 0x1FFFF, p.y);
    }
}

// ---------------- SpMM: one wave per row, scalar edge loads, nt out-store ----------------
__global__ __launch_bounds__(256) void spmm_kernel(
    const ushort* __restrict__ h, const int2* __restrict__ pairs,
    const int* __restrict__ row_start, float* __restrict__ out)
{
    const int wid  = blockIdx.x * 4 + (threadIdx.x >> 6);
    const int lane = threadIdx.x & 63;
    if (wid >= N_NODES) return;
    // segment bounds are wave-uniform: force scalar so edge loads become s_load
    const int s = __builtin_amdgcn_readfirstlane(row_start[wid]);
    const int e = __builtin_amdgcn_readfirstlane(row_start[wid + 1]);
    const int loff = lane * 4;
    float ax = 0.f, ay = 0.f, az = 0.f, aw = 0.f;

    int j = s;
    for (; j + 8 <= e; j += 8) {
        const int4* p4 = (const int4*)(pairs + j);   // uniform address -> s_load_dwordx4
        int4 q0 = p4[0], q1 = p4[1], q2 = p4[2], q3 = p4[3];
        int   c[8] = { q0.x, q0.z, q1.x, q1.z, q2.x, q2.z, q3.x, q3.z };
        float v[8] = { __int_as_float(q0.y), __int_as_float(q0.w),
                       __int_as_float(q1.y), __int_as_float(q1.w),
                       __int_as_float(q2.y), __int_as_float(q2.w),
                       __int_as_float(q3.y), __int_as_float(q3.w) };
        ushort4 hv[8];
        #pragma unroll
        for (int t = 0; t < 8; ++t)
            hv[t] = *(const ushort4*)(h + (size_t)c[t] * DD + loff);
        #pragma unroll
        for (int t = 0; t < 8; ++t) {
            ax += v[t] * bf2f(hv[t].x);
            ay += v[t] * bf2f(hv[t].y);
            az += v[t] * bf2f(hv[t].z);
            aw += v[t] * bf2f(hv[t].w);
        }
    }
    for (; j < e; ++j) {
        int2 p = pairs[j];                           // uniform -> s_load
        const float vv = __int_as_float(p.y);
        const ushort4 hv = *(const ushort4*)(h + (size_t)p.x * DD + loff);
        ax += vv * bf2f(hv.x);
        ay += vv * bf2f(hv.y);
        az += vv * bf2f(hv.z);
        aw += vv * bf2f(hv.w);
    }
    f32x4 o = { ax, ay, az, aw };
    __builtin_nontemporal_store(o, (f32x4*)(out + (size_t)wid * DD + loff));
}

extern "C" void kernel_launch(void* const* d_in, const int* in_sizes, int n_in,
                              void* d_out, int out_size, void* d_ws, size_t ws_size,
                              hipStream_t stream)
{
    const float* x        = (const float*)d_in[0];
    const float* W        = (const float*)d_in[1];
    const float* edge_val = (const float*)d_in[2];
    const int*   edge_row = (const int*)d_in[3];
    const int*   edge_col = (const int*)d_in[4];
    float* out = (float*)d_out;

    char* ws = (char*)d_ws;
    size_t off = 0;
    auto alloc = [&](size_t bytes) {
        void* p = ws + off;
        off = (off + bytes + 255) & ~(size_t)255;
        return p;
    };
    ushort* h         = (ushort*)alloc((size_t)N_NODES * DD * sizeof(ushort)); // 51.2 MB
    int2*   pairsA    = (int2*)  alloc((size_t)N_EDGES * sizeof(int2));        // 25.6 MB
    int2*   pairsB    = (int2*)  alloc((size_t)N_EDGES * sizeof(int2));        // 25.6 MB
    ushort* wb        = (ushort*)alloc((size_t)DD * DD * sizeof(ushort));
    int*    bcnt      = (int*)   alloc((size_t)NBKT * sizeof(int));
    int*    bbase     = (int*)   alloc((size_t)(NBKT + 1) * sizeof(int));
    int*    gcur      = (int*)   alloc((size_t)NBKT * sizeof(int));
    int*    row_start = (int*)   alloc((size_t)(N_NODES + 1) * sizeof(int));
    (void)ws_size;

    hipMemsetAsync(bcnt, 0, (size_t)NBKT * sizeof(int), stream);

    wconv_kernel<<<(DD * DD / 4) / 256, 256, 0, stream>>>(W, wb);

    dim3 ggrid((N_NODES + GBM - 1) / GBM, DD / GBN);
    gemm_mfma<<<ggrid, 256, 0, stream>>>(x, wb, h);

    coarse_hist<<<NABLK, 256, 0, stream>>>(edge_row, bcnt);
    bucket_scan<<<1, 1024, 0, stream>>>(bcnt, bbase, gcur, row_start);
    passA<<<NABLK, 256, 0, stream>>>(edge_row, edge_col, edge_val, gcur, pairsA);
    passB<<<NBKT, 256, 0, stream>>>(pairsA, bbase, pairsB, row_start);

    int spmm_blocks = (N_NODES + 3) / 4;
    spmm_kernel<<<spmm_blocks, 256, 0, stream>>>(h, pairsB, row_start, out);
}